// Round 4
// baseline (526.057 us; speedup 1.0000x reference)
//
#include <hip/hip_runtime.h>

#define NLAT 192
#define NPTS 40320
#define MMAX 96
#define LMAX 96
#define NV   100
#define MAXN 400
#define NB   400   // total B rows = 4 * NV

__device__ __forceinline__ float bits2f(unsigned int b) {
    union { unsigned int i; float f; } v; v.i = b; return v.f;
}
__device__ __forceinline__ unsigned int f2bf(float f) {
    // RNE float -> bf16 (values are finite, no NaN handling needed)
    union { float f; unsigned int i; } v; v.f = f;
    return (v.i + 0x7FFFu + ((v.i >> 16) & 1u)) >> 16;
}

// ring j: number of points n_j and flat start offset (closed form, north->south)
__device__ __forceinline__ void ring_info(int j, int& n, int& start) {
    if (j < 96) { n = 20 + 4 * j; start = 2 * j * j + 18 * j; }
    else { int jj = j - 96; n = 400 - 4 * jj; start = 20160 + 402 * jj - 2 * jj * jj; }
}

// Kernel 1: per-ring truncated real DFT.
// fh[Brel][j][m] = sum_k x[c0+Brel, start_j+k] * dft[j,k,m]   (complex, m-contiguous)
// dft dtype probed on-device: dword1 == 0 -> fp32 interleaved pairs,
//                             dword1 != 0 -> bf16 interleaved pairs (0x00003D4D).
// Block: (ring j, B-tile of 32). 256 threads: mi = tid&15, bl = tid>>4.
__global__ __launch_bounds__(256) void dft_ring_kernel(
    const float* __restrict__ data,   // [4][NPTS][NV] fp32
    const void*  __restrict__ dft,    // [NLAT][MAXN][MMAX][2] bf16 or fp32
    float* __restrict__ fh,           // [cn][NLAT][MMAX][2] fp32
    int c0, int cn) {
    int j = blockIdx.x;
    int n, start;
    ring_info(j, n, start);

    const bool dft_bf16 = (((const unsigned int*)dft)[1] != 0u);

    __shared__ float xs[32][401];
    int tid = threadIdx.x;
    int row0 = blockIdx.y * 32;

    // stage x tile: 32 B-rows x n_j points
    {
        int bi = tid & 31;
        int Brel = row0 + bi;
        bool ok = Brel < cn;
        int B = c0 + (ok ? Brel : 0);
        int bb = B / NV, vv = B % NV;
        const float* src = data + (size_t)bb * NPTS * NV + (size_t)start * NV + vv;
        for (int k = tid >> 5; k < n; k += 8)
            xs[bi][k] = ok ? src[(size_t)k * NV] : 0.f;
    }
    __syncthreads();

    int mi = tid & 15;        // complex-pair unit index: u = mi + 16q, q=0..2
    int bl = tid >> 4;        // row pair: rows 2*bl, 2*bl+1
    int r0 = 2 * bl;

    float4 acc[2][3];         // acc[r][q] = (re0, im0, re1, im1) of complex 2u, 2u+1
#pragma unroll
    for (int r = 0; r < 2; ++r)
#pragma unroll
        for (int q = 0; q < 3; ++q) acc[r][q] = make_float4(0.f, 0.f, 0.f, 0.f);

    if (dft_bf16) {
        // bf16 pairs: 48 uint2 units per (j,k); uint2 = 2 complex (re,im,re,im)
        const uint2* db = (const uint2*)dft + (size_t)j * MAXN * 48 + mi;
        for (int k = 0; k < n; ++k) {
            float x0 = xs[r0][k];
            float x1 = xs[r0 + 1][k];
            const uint2* dk = db + (size_t)k * 48;
#pragma unroll
            for (int q = 0; q < 3; ++q) {
                uint2 w = dk[16 * q];
                float re0 = bits2f(w.x << 16), im0 = bits2f(w.x & 0xFFFF0000u);
                float re1 = bits2f(w.y << 16), im1 = bits2f(w.y & 0xFFFF0000u);
                acc[0][q].x += x0 * re0; acc[0][q].y += x0 * im0;
                acc[0][q].z += x0 * re1; acc[0][q].w += x0 * im1;
                acc[1][q].x += x1 * re0; acc[1][q].y += x1 * im0;
                acc[1][q].z += x1 * re1; acc[1][q].w += x1 * im1;
            }
        }
    } else {
        // fp32 pairs: 48 float4 units per (j,k)
        const float4* d4 = (const float4*)dft + (size_t)j * MAXN * 48 + mi;
        for (int k = 0; k < n; ++k) {
            float x0 = xs[r0][k];
            float x1 = xs[r0 + 1][k];
            const float4* dk = d4 + (size_t)k * 48;
#pragma unroll
            for (int q = 0; q < 3; ++q) {
                float4 d = dk[16 * q];
                acc[0][q].x += x0 * d.x; acc[0][q].y += x0 * d.y;
                acc[0][q].z += x0 * d.z; acc[0][q].w += x0 * d.w;
                acc[1][q].x += x1 * d.x; acc[1][q].y += x1 * d.y;
                acc[1][q].z += x1 * d.z; acc[1][q].w += x1 * d.w;
            }
        }
    }

#pragma unroll
    for (int r = 0; r < 2; ++r) {
        int Brel = row0 + r0 + r;
        if (Brel < cn) {
            float4* o = (float4*)fh + ((size_t)Brel * NLAT + j) * 48 + mi;
#pragma unroll
            for (int q = 0; q < 3; ++q) o[16 * q] = acc[r][q];
        }
    }
}

// Kernel 2: Legendre contraction. out[c0+Brel, l, m] = sum_j fh[Brel,j,m] * leg[l,m,j]
// Output is bf16 (re,im) pairs, one packed uint per complex.
// Block: (m, B-tile of 16). 256 threads: bi = tid&15 (B row), li = tid>>4; l = li+16q.
__global__ __launch_bounds__(256) void leg_kernel(
    const float* __restrict__ fh,     // [cn][NLAT][MMAX][2] fp32
    const float* __restrict__ leg,    // [LMAX][MMAX][NLAT] fp32
    unsigned int* __restrict__ out,   // [4][LMAX][MMAX][NV] packed bf16 (re|im<<16)
    int c0, int cn) {
    int m = blockIdx.x;
    int tid = threadIdx.x;
    int bi = tid & 15, li = tid >> 4;
    int Brel = blockIdx.y * 16 + bi;
    int Brc = Brel < cn ? Brel : cn - 1;

    const float2* f = (const float2*)fh + (size_t)Brc * NLAT * MMAX + m;
    const float* lp[6];
#pragma unroll
    for (int q = 0; q < 6; ++q)
        lp[q] = leg + ((size_t)(li + 16 * q) * MMAX + m) * NLAT;

    float2 acc[6];
#pragma unroll
    for (int q = 0; q < 6; ++q) acc[q] = make_float2(0.f, 0.f);

    for (int j = 0; j < NLAT; ++j) {
        float2 fv = f[(size_t)j * MMAX];
#pragma unroll
        for (int q = 0; q < 6; ++q) {
            float lv = lp[q][j];
            acc[q].x += fv.x * lv;
            acc[q].y += fv.y * lv;
        }
    }

    if (Brel < cn) {
        int B = c0 + Brel;
        int bb = B / NV, vv = B % NV;
#pragma unroll
        for (int q = 0; q < 6; ++q) {
            int l = li + 16 * q;
            out[(((size_t)bb * LMAX + l) * MMAX + m) * NV + vv] =
                f2bf(acc[q].x) | (f2bf(acc[q].y) << 16);
        }
    }
}

extern "C" void kernel_launch(void* const* d_in, const int* in_sizes, int n_in,
                              void* d_out, int out_size, void* d_ws, size_t ws_size,
                              hipStream_t stream) {
    if (n_in != 3) return;  // unexpected packing: fail validation cleanly, don't fault

    const float* data = (const float*)d_in[0];
    const void*  dft  = d_in[1];
    const float* leg  = (const float*)d_in[2];
    unsigned int* out = (unsigned int*)d_out;
    float* fh = (float*)d_ws;

    // adaptive B-chunking so fp32 f_hat fits ws_size (147456 bytes per B row)
    const size_t rowb = (size_t)NLAT * MMAX * 2 * sizeof(float);
    size_t maxrows = ws_size / rowb;
    int chunk = (int)(maxrows < (size_t)NB ? maxrows : (size_t)NB);
    if (chunk <= 0) return;

    for (int c0 = 0; c0 < NB; c0 += chunk) {
        int cn = NB - c0 < chunk ? NB - c0 : chunk;
        dim3 g1(NLAT, (cn + 31) / 32);
        dft_ring_kernel<<<g1, dim3(256), 0, stream>>>(data, dft, fh, c0, cn);
        dim3 g2(MMAX, (cn + 15) / 16);
        leg_kernel<<<g2, dim3(256), 0, stream>>>(fh, leg, out, c0, cn);
    }
}

// Round 5
// 400.908 us; speedup vs baseline: 1.3122x; 1.3122x over previous
//
#include <hip/hip_runtime.h>

#define NLAT 192
#define NPTS 40320
#define MMAX 96
#define LMAX 96
#define NV   100
#define MAXN 400
#define NB   400   // total B rows = 4 * NV

static __device__ __forceinline__ float bits2f(unsigned int b) {
    union { unsigned int i; float f; } v; v.i = b; return v.f;
}
static __device__ __forceinline__ unsigned int f2bf(float f) {
    union { float f; unsigned int i; } v; v.f = f;
    return (v.i + 0x7FFFu + ((v.i >> 16) & 1u)) >> 16;
}

// ring j: number of points n_j and flat start offset (closed form, north->south)
__device__ __forceinline__ void ring_info(int j, int& n, int& start) {
    if (j < 96) { n = 20 + 4 * j; start = 2 * j * j + 18 * j; }
    else { int jj = j - 96; n = 400 - 4 * jj; start = 20160 + 402 * jj - 2 * jj * jj; }
}

// Kernel 1: per-ring truncated real DFT.
// fh[j][m][Brel] (float2, B contiguous) = sum_k x[c0+Brel, start_j+k] * dft[j,k,m]
// dft dtype probed on-device: dword1 == 0 -> fp32 pairs, != 0 -> bf16 pairs.
// Block: (ring jx interleaved, B-tile of 32). 256 threads: mi = tid&15, bl = tid>>4.
// Thread covers rows {bl, bl+16} x 12 m-values (units mi+16q, q=0..2).
__global__ __launch_bounds__(256) void dft_ring_kernel(
    const float* __restrict__ data,   // [4][NPTS][NV] fp32
    const void*  __restrict__ dft,    // [NLAT][MAXN][MMAX][2] bf16 or fp32
    float2* __restrict__ fh,          // [NLAT][MMAX][cn] float2
    int c0, int cn) {
    int jx = blockIdx.x;
    int j = (jx >> 1) + ((jx & 1) ? 96 : 0);   // interleave small/large rings
    int n, start;
    ring_info(j, n, start);

    const bool dft_bf16 = (((const unsigned int*)dft)[1] != 0u);

    __shared__ float xs[MAXN][32];    // k-major: read xs[k][row], bank = row
    int tid = threadIdx.x;
    int row0 = blockIdx.y * 32;

    // stage x tile: 32 B-rows x n_j points
    {
        int bi = tid & 31;
        int Brel = row0 + bi;
        bool ok = Brel < cn;
        int B = c0 + (ok ? Brel : 0);
        int bb = B / NV, vv = B % NV;
        const float* src = data + (size_t)bb * NPTS * NV + (size_t)start * NV + vv;
        for (int k = tid >> 5; k < n; k += 8)
            xs[k][bi] = ok ? src[(size_t)k * NV] : 0.f;
    }
    __syncthreads();

    int mi = tid & 15;        // complex-pair unit u = mi + 16q, m = 2u, 2u+1
    int bl = tid >> 4;        // rows bl, bl+16

    float4 acc[2][3];         // acc[r][q] = (re0, im0, re1, im1) for unit mi+16q
#pragma unroll
    for (int r = 0; r < 2; ++r)
#pragma unroll
        for (int q = 0; q < 3; ++q) acc[r][q] = make_float4(0.f, 0.f, 0.f, 0.f);

    if (dft_bf16) {
        const uint2* db = (const uint2*)dft + (size_t)j * MAXN * 48 + mi;
        for (int k = 0; k < n; ++k) {
            float x0 = xs[k][bl];
            float x1 = xs[k][bl + 16];
            const uint2* dk = db + (size_t)k * 48;
#pragma unroll
            for (int q = 0; q < 3; ++q) {
                uint2 w = dk[16 * q];
                float re0 = bits2f(w.x << 16), im0 = bits2f(w.x & 0xFFFF0000u);
                float re1 = bits2f(w.y << 16), im1 = bits2f(w.y & 0xFFFF0000u);
                acc[0][q].x += x0 * re0; acc[0][q].y += x0 * im0;
                acc[0][q].z += x0 * re1; acc[0][q].w += x0 * im1;
                acc[1][q].x += x1 * re0; acc[1][q].y += x1 * im0;
                acc[1][q].z += x1 * re1; acc[1][q].w += x1 * im1;
            }
        }
    } else {
        const float4* d4 = (const float4*)dft + (size_t)j * MAXN * 48 + mi;
        for (int k = 0; k < n; ++k) {
            float x0 = xs[k][bl];
            float x1 = xs[k][bl + 16];
            const float4* dk = d4 + (size_t)k * 48;
#pragma unroll
            for (int q = 0; q < 3; ++q) {
                float4 d = dk[16 * q];
                acc[0][q].x += x0 * d.x; acc[0][q].y += x0 * d.y;
                acc[0][q].z += x0 * d.z; acc[0][q].w += x0 * d.w;
                acc[1][q].x += x1 * d.x; acc[1][q].y += x1 * d.y;
                acc[1][q].z += x1 * d.z; acc[1][q].w += x1 * d.w;
            }
        }
    }

    // write fh[j][m][Brel]: lanes (bl 0..3 in wave) x r cover contiguous B spans
#pragma unroll
    for (int r = 0; r < 2; ++r) {
        int Brel = row0 + bl + 16 * r;
        if (Brel < cn) {
#pragma unroll
            for (int q = 0; q < 3; ++q) {
                int m0 = 2 * (mi + 16 * q);
                fh[((size_t)j * MMAX + m0) * cn + Brel] =
                    make_float2(acc[r][q].x, acc[r][q].y);
                fh[((size_t)j * MMAX + m0 + 1) * cn + Brel] =
                    make_float2(acc[r][q].z, acc[r][q].w);
            }
        }
    }
}

// Kernel 2: Legendre contraction. out[c0+Brel, l, m] = sum_j fh[j][m][Brel] * leg[l,m,j]
// Block: (m, B-tile of 16). 256 threads: bi = tid&15 (B lane, coalesced), li = tid>>4.
__global__ __launch_bounds__(256) void leg_kernel(
    const float2* __restrict__ fh,    // [NLAT][MMAX][cn] float2
    const float* __restrict__ leg,    // [LMAX][MMAX][NLAT] fp32
    unsigned int* __restrict__ out,   // [4][LMAX][MMAX][NV] packed bf16 (re|im<<16)
    int c0, int cn) {
    int m = blockIdx.x;
    int tid = threadIdx.x;
    int bi = tid & 15, li = tid >> 4;
    int Brel = blockIdx.y * 16 + bi;
    int Brc = Brel < cn ? Brel : cn - 1;

    const float2* f = fh + (size_t)m * cn + Brc;   // + j*MMAX*cn per j
    const float* lp[6];
#pragma unroll
    for (int q = 0; q < 6; ++q)
        lp[q] = leg + ((size_t)(li + 16 * q) * MMAX + m) * NLAT;

    float2 acc[6];
#pragma unroll
    for (int q = 0; q < 6; ++q) acc[q] = make_float2(0.f, 0.f);

    const size_t jstride = (size_t)MMAX * cn;
#pragma unroll 4
    for (int j = 0; j < NLAT; ++j) {
        float2 fv = f[j * jstride];
#pragma unroll
        for (int q = 0; q < 6; ++q) {
            float lv = lp[q][j];
            acc[q].x += fv.x * lv;
            acc[q].y += fv.y * lv;
        }
    }

    if (Brel < cn) {
        int B = c0 + Brel;
        int bb = B / NV, vv = B % NV;
#pragma unroll
        for (int q = 0; q < 6; ++q) {
            int l = li + 16 * q;
            out[(((size_t)bb * LMAX + l) * MMAX + m) * NV + vv] =
                f2bf(acc[q].x) | (f2bf(acc[q].y) << 16);
        }
    }
}

extern "C" void kernel_launch(void* const* d_in, const int* in_sizes, int n_in,
                              void* d_out, int out_size, void* d_ws, size_t ws_size,
                              hipStream_t stream) {
    if (n_in != 3) return;

    const float* data = (const float*)d_in[0];
    const void*  dft  = d_in[1];
    const float* leg  = (const float*)d_in[2];
    unsigned int* out = (unsigned int*)d_out;
    float2* fh = (float2*)d_ws;

    // adaptive B-chunking so fp32 f_hat fits ws_size (147456 bytes per B row)
    const size_t rowb = (size_t)NLAT * MMAX * 2 * sizeof(float);
    size_t maxrows = ws_size / rowb;
    int chunk = (int)(maxrows < (size_t)NB ? maxrows : (size_t)NB);
    if (chunk <= 0) return;

    for (int c0 = 0; c0 < NB; c0 += chunk) {
        int cn = NB - c0 < chunk ? NB - c0 : chunk;
        dim3 g1(NLAT, (cn + 31) / 32);
        dft_ring_kernel<<<g1, dim3(256), 0, stream>>>(data, dft, fh, c0, cn);
        dim3 g2(MMAX, (cn + 15) / 16);
        leg_kernel<<<g2, dim3(256), 0, stream>>>(fh, leg, out, c0, cn);
    }
}

// Round 6
// 169.742 us; speedup vs baseline: 3.0992x; 2.3619x over previous
//
#include <hip/hip_runtime.h>

#define NLAT 192
#define NPTS 40320
#define MMAX 96
#define LMAX 96
#define NV   100
#define MAXN 400
#define NB   400   // total B rows = 4 * NV

typedef __attribute__((ext_vector_type(8))) short short8v;  // 8 bf16 (4 VGPRs)
typedef __attribute__((ext_vector_type(4))) float f32x4;

#define ASTR 56   // shorts per LDS row: 112 B = 16-aligned (b128 ok), 2-way banks (free)
#define XSTR 56

static __device__ __forceinline__ float bits2f(unsigned int b) {
    union { unsigned int i; float f; } v; v.i = b; return v.f;
}
static __device__ __forceinline__ unsigned int f2bf(float f) {
    union { float f; unsigned int i; } v; v.f = f;
    return (v.i + 0x7FFFu + ((v.i >> 16) & 1u)) >> 16;
}

// Kernel 1 (MFMA): per-ring truncated real DFT as bf16 GEMM.
// fh[j][mm][B] (planar: mm = m + 96*c, c=0 re / 1 im) = sum_k Dt[mm][k] * X[k][B]
// x is split hi+lo bf16 (two MFMAs) to retain ~fp32 precision.
// Block: ring-pair p -> rings (p, 96+p), n0+n1 = 420 (uniform work);
//        B-tile of 50 (one half of one bb), N padded to 64.
// 256 threads = 4 waves; wave w owns m-tiles {3w,3w+1,3w+2} x 4 n-tiles.
__global__ __launch_bounds__(256, 4) void dft_mfma_kernel(
    const float* __restrict__ data,          // [4][NPTS][NV] fp32
    const unsigned int* __restrict__ dftw,   // [NLAT][MAXN][96] bf16 pair (re | im<<16)
    float* __restrict__ fh,                  // [NLAT][192][cn] planar fp32
    int c0, int cn)
{
    __shared__ short A_lds[192 * ASTR];      // Dt rows: re-plane 0..95, im-plane 96..191
    __shared__ short Xh_lds[64 * XSTR];      // X hi tile [c][k]
    __shared__ short Xl_lds[64 * XSTR];      // X lo tile [c][k]

    const int p   = blockIdx.x;              // ring pair id 0..95
    const int bt  = blockIdx.y;              // 50-col B tile
    const int tid = threadIdx.x;
    const int w   = tid >> 6;                // wave 0..3
    const int l   = tid & 63;
    const int lr  = l & 15;
    const int kg  = l >> 4;

    const int Bb = c0 + bt * 50;
    const int bb = Bb / NV;
    const int vb = Bb % NV;                  // 0 or 50
    const float* dbase = data + (size_t)bb * NPTS * NV + vb;

    for (int rr = 0; rr < 2; ++rr) {
        int j, n, start;
        if (rr == 0) { j = p;      n = 20 + 4 * p;  start = 2 * p * p + 18 * p; }
        else         { j = 96 + p; n = 400 - 4 * p; start = 20160 + 402 * p - 2 * p * p; }

        f32x4 acc[3][4];
#pragma unroll
        for (int i = 0; i < 3; ++i)
#pragma unroll
            for (int nt = 0; nt < 4; ++nt) acc[i][nt] = (f32x4){0.f, 0.f, 0.f, 0.f};

        for (int k0 = 0; k0 < n; k0 += 32) {
            __syncthreads();   // protect previous step's LDS reads

            // ---- stage A: Dt[192 mm][32 k] from dft words (transpose + deinterleave)
#pragma unroll
            for (int s = 0; s < 3; ++s) {
                int q  = tid + 256 * s;      // 0..767
                int kq = q / 96;             // k-quad 0..7
                int m  = q - kq * 96;        // 0..95
                int kb = k0 + kq * 4;
                unsigned int w0 = 0, w1 = 0, w2 = 0, w3 = 0;
                const unsigned int* dp = dftw + ((size_t)j * MAXN + kb) * 96 + m;
                if (kb     < n) w0 = dp[0];
                if (kb + 1 < n) w1 = dp[96];
                if (kb + 2 < n) w2 = dp[192];
                if (kb + 3 < n) w3 = dp[288];
                uint2 re = { (w0 & 0xFFFFu) | (w1 << 16), (w2 & 0xFFFFu) | (w3 << 16) };
                uint2 im = { (w0 >> 16) | (w1 & 0xFFFF0000u), (w2 >> 16) | (w3 & 0xFFFF0000u) };
                *(uint2*)&A_lds[m * ASTR + kq * 4]        = re;
                *(uint2*)&A_lds[(96 + m) * ASTR + kq * 4] = im;
            }

            // ---- stage X: [64 c][32 k] hi/lo bf16 split
#pragma unroll
            for (int s = 0; s < 4; ++s) {
                int q  = tid + 256 * s;      // 0..1023
                int c  = q & 63;
                int kp = q >> 6;             // k-pair 0..15
                int k  = k0 + 2 * kp;
                float x0 = 0.f, x1 = 0.f;
                if (c < 50) {
                    const float* sp = dbase + (size_t)(start + k) * NV + c;
                    if (k     < n) x0 = sp[0];
                    if (k + 1 < n) x1 = sp[NV];
                }
                unsigned int h0 = f2bf(x0), h1 = f2bf(x1);
                float r0 = x0 - bits2f(h0 << 16);
                float r1 = x1 - bits2f(h1 << 16);
                unsigned int l0 = f2bf(r0), l1 = f2bf(r1);
                ((unsigned int*)Xh_lds)[c * (XSTR / 2) + kp] = h0 | (h1 << 16);
                ((unsigned int*)Xl_lds)[c * (XSTR / 2) + kp] = l0 | (l1 << 16);
            }
            __syncthreads();

            // ---- compute: 3 A-frags x 4 B-tiles x (hi,lo)
            short8v a0 = *(const short8v*)&A_lds[((3 * w + 0) * 16 + lr) * ASTR + kg * 8];
            short8v a1 = *(const short8v*)&A_lds[((3 * w + 1) * 16 + lr) * ASTR + kg * 8];
            short8v a2 = *(const short8v*)&A_lds[((3 * w + 2) * 16 + lr) * ASTR + kg * 8];
#pragma unroll
            for (int nt = 0; nt < 4; ++nt) {
                short8v bh = *(const short8v*)&Xh_lds[(nt * 16 + lr) * XSTR + kg * 8];
                short8v bl = *(const short8v*)&Xl_lds[(nt * 16 + lr) * XSTR + kg * 8];
                acc[0][nt] = __builtin_amdgcn_mfma_f32_16x16x32_bf16(a0, bh, acc[0][nt], 0, 0, 0);
                acc[1][nt] = __builtin_amdgcn_mfma_f32_16x16x32_bf16(a1, bh, acc[1][nt], 0, 0, 0);
                acc[2][nt] = __builtin_amdgcn_mfma_f32_16x16x32_bf16(a2, bh, acc[2][nt], 0, 0, 0);
                acc[0][nt] = __builtin_amdgcn_mfma_f32_16x16x32_bf16(a0, bl, acc[0][nt], 0, 0, 0);
                acc[1][nt] = __builtin_amdgcn_mfma_f32_16x16x32_bf16(a1, bl, acc[1][nt], 0, 0, 0);
                acc[2][nt] = __builtin_amdgcn_mfma_f32_16x16x32_bf16(a2, bl, acc[2][nt], 0, 0, 0);
            }
        }

        // ---- epilogue: C/D layout col=lane&15 (B), row=(lane>>4)*4+reg (mm)
#pragma unroll
        for (int i = 0; i < 3; ++i)
#pragma unroll
            for (int nt = 0; nt < 4; ++nt) {
                int c = nt * 16 + lr;
                if (c < 50) {
                    int Brel = bt * 50 + c;
                    int mm0 = (3 * w + i) * 16 + kg * 4;
                    float* op = fh + ((size_t)j * 192 + mm0) * cn + Brel;
#pragma unroll
                    for (int r = 0; r < 4; ++r)
                        op[(size_t)r * cn] = acc[i][nt][r];
                }
            }
    }
}

// Kernel 2: Legendre contraction (planar fh).
// out[B,l,m] = sum_j (fh_re[j][m][B] + i*fh_im) * leg[l,m,j]
__global__ __launch_bounds__(256) void leg_kernel(
    const float* __restrict__ fh,     // [NLAT][192][cn] planar
    const float* __restrict__ leg,    // [LMAX][MMAX][NLAT] fp32
    unsigned int* __restrict__ out,   // [4][LMAX][MMAX][NV] packed bf16 (re|im<<16)
    int c0, int cn) {
    int m = blockIdx.x;
    int tid = threadIdx.x;
    int bi = tid & 15, li = tid >> 4;
    int Brel = blockIdx.y * 16 + bi;
    int Brc = Brel < cn ? Brel : cn - 1;

    const float* fre = fh + (size_t)m * cn + Brc;
    const float* fim = fre + (size_t)96 * cn;
    const float* lp[6];
#pragma unroll
    for (int q = 0; q < 6; ++q)
        lp[q] = leg + ((size_t)(li + 16 * q) * MMAX + m) * NLAT;

    float2 acc[6];
#pragma unroll
    for (int q = 0; q < 6; ++q) acc[q] = make_float2(0.f, 0.f);

    const size_t jstr = (size_t)192 * cn;
#pragma unroll 4
    for (int j = 0; j < NLAT; ++j) {
        float fr = fre[j * jstr];
        float fi = fim[j * jstr];
#pragma unroll
        for (int q = 0; q < 6; ++q) {
            float lv = lp[q][j];
            acc[q].x += fr * lv;
            acc[q].y += fi * lv;
        }
    }

    if (Brel < cn) {
        int B = c0 + Brel;
        int bb = B / NV, vv = B % NV;
#pragma unroll
        for (int q = 0; q < 6; ++q) {
            int l = li + 16 * q;
            out[(((size_t)bb * LMAX + l) * MMAX + m) * NV + vv] =
                f2bf(acc[q].x) | (f2bf(acc[q].y) << 16);
        }
    }
}

extern "C" void kernel_launch(void* const* d_in, const int* in_sizes, int n_in,
                              void* d_out, int out_size, void* d_ws, size_t ws_size,
                              hipStream_t stream) {
    if (n_in != 3) return;

    const float* data = (const float*)d_in[0];
    const unsigned int* dftw = (const unsigned int*)d_in[1];
    const float* leg  = (const float*)d_in[2];
    unsigned int* out = (unsigned int*)d_out;
    float* fh = (float*)d_ws;

    // B-chunking in multiples of 100 so fp32 f_hat fits ws (147456 B per B row)
    const size_t rowb = (size_t)NLAT * 192 * sizeof(float);
    size_t maxrows = ws_size / rowb;
    int chunk = (int)((maxrows / 100) * 100);
    if (chunk > NB) chunk = NB;
    if (chunk < 100) return;

    for (int c0 = 0; c0 < NB; c0 += chunk) {
        int cn = NB - c0 < chunk ? NB - c0 : chunk;
        dim3 g1(96, cn / 50);
        dft_mfma_kernel<<<g1, dim3(256), 0, stream>>>(data, dftw, fh, c0, cn);
        dim3 g2(MMAX, (cn + 15) / 16);
        leg_kernel<<<g2, dim3(256), 0, stream>>>(fh, leg, out, c0, cn);
    }
}

// Round 8
// 96.562 us; speedup vs baseline: 5.4479x; 1.7579x over previous
//
#include <hip/hip_runtime.h>

#define NLAT 192
#define NPTS 40320
#define MMAX 96
#define LMAX 96
#define NV   100
#define MAXN 400
#define NB   400   // total B rows = 4 * NV

typedef __attribute__((ext_vector_type(8))) short short8v;  // 8 bf16 (4 VGPRs)
typedef __attribute__((ext_vector_type(4))) float f32x4;

#define ASTR 56   // K1 LDS row stride (shorts): 112 B, 16-aligned, 2-way banks
#define XSTR 56
#define FSTR 40   // K2 LDS row stride (shorts): 80 B, 16-aligned, 2-way banks on b128

static __device__ __forceinline__ float bits2f(unsigned int b) {
    union { unsigned int i; float f; } v; v.i = b; return v.f;
}
static __device__ __forceinline__ unsigned int f2bf(float f) {
    union { float f; unsigned int i; } v; v.f = f;
    return (v.i + 0x7FFFu + ((v.i >> 16) & 1u)) >> 16;
}

// ---------------- K0: split leg fp32 -> bf16 hi/lo, relayout [l][m][j] -> [m][l][j]
__global__ __launch_bounds__(256) void leg_conv_kernel(
    const float* __restrict__ leg,    // [96 l][96 m][192 j]
    unsigned short* __restrict__ legh,
    unsigned short* __restrict__ legl)
{
    int idx = blockIdx.x * 256 + threadIdx.x;
    if (idx >= 96 * 96 * 192) return;
    int j = idx % 192;
    int lm = idx / 192;
    int m = lm % 96, l = lm / 96;
    float v = leg[idx];
    unsigned int h = f2bf(v);
    unsigned int lo = f2bf(v - bits2f(h << 16));
    size_t o = ((size_t)m * 96 + l) * 192 + j;
    legh[o] = (unsigned short)h;
    legl[o] = (unsigned short)lo;
}

// ---------------- K1 (MFMA): per-ring truncated real DFT as bf16 GEMM.
// fh_hi/lo[j][mm][B] (bf16 planar: mm = m + 96*c, c=0 re / 1 im)
// Block: (B-tile bt = blockIdx.x, ring-pair p = blockIdx.y) -> same-p blocks
// are consecutive block ids (XCD L2 reuse of the dft slice).
__global__ __launch_bounds__(256, 4) void dft_mfma_kernel(
    const float* __restrict__ data,          // [4][NPTS][NV] fp32
    const unsigned int* __restrict__ dftw,   // [NLAT][MAXN][96] bf16 pair (re | im<<16)
    unsigned short* __restrict__ fh_hi,      // [NLAT][192][cn] bf16
    unsigned short* __restrict__ fh_lo,
    int c0, int cn)
{
    __shared__ short A_lds[192 * ASTR];      // Dt rows: re 0..95, im 96..191
    __shared__ short Xh_lds[64 * XSTR];
    __shared__ short Xl_lds[64 * XSTR];

    const int bt  = blockIdx.x;              // 50-col B tile
    const int p   = blockIdx.y;              // ring pair 0..95
    const int tid = threadIdx.x;
    const int w   = tid >> 6;
    const int l   = tid & 63;
    const int lr  = l & 15;
    const int kg  = l >> 4;

    const int Bb = c0 + bt * 50;
    const int bb = Bb / NV;
    const int vb = Bb % NV;
    const float* dbase = data + (size_t)bb * NPTS * NV + vb;

    for (int rr = 0; rr < 2; ++rr) {
        int j, n, start;
        if (rr == 0) { j = p;      n = 20 + 4 * p;  start = 2 * p * p + 18 * p; }
        else         { j = 96 + p; n = 400 - 4 * p; start = 20160 + 402 * p - 2 * p * p; }

        f32x4 acc[3][4];
#pragma unroll
        for (int i = 0; i < 3; ++i)
#pragma unroll
            for (int nt = 0; nt < 4; ++nt) acc[i][nt] = (f32x4){0.f, 0.f, 0.f, 0.f};

        for (int k0 = 0; k0 < n; k0 += 32) {
            __syncthreads();

            // stage A: Dt[192 mm][32 k] (transpose + re/im deinterleave)
#pragma unroll
            for (int s = 0; s < 3; ++s) {
                int q  = tid + 256 * s;
                int kq = q / 96;
                int m  = q - kq * 96;
                int kb = k0 + kq * 4;
                unsigned int w0 = 0, w1 = 0, w2 = 0, w3 = 0;
                const unsigned int* dp = dftw + ((size_t)j * MAXN + kb) * 96 + m;
                if (kb     < n) w0 = dp[0];
                if (kb + 1 < n) w1 = dp[96];
                if (kb + 2 < n) w2 = dp[192];
                if (kb + 3 < n) w3 = dp[288];
                uint2 re = { (w0 & 0xFFFFu) | (w1 << 16), (w2 & 0xFFFFu) | (w3 << 16) };
                uint2 im = { (w0 >> 16) | (w1 & 0xFFFF0000u), (w2 >> 16) | (w3 & 0xFFFF0000u) };
                *(uint2*)&A_lds[m * ASTR + kq * 4]        = re;
                *(uint2*)&A_lds[(96 + m) * ASTR + kq * 4] = im;
            }

            // stage X: [64 c][32 k] hi/lo bf16 split
#pragma unroll
            for (int s = 0; s < 4; ++s) {
                int q  = tid + 256 * s;
                int c  = q & 63;
                int kp = q >> 6;
                int k  = k0 + 2 * kp;
                float x0 = 0.f, x1 = 0.f;
                if (c < 50) {
                    const float* sp = dbase + (size_t)(start + k) * NV + c;
                    if (k     < n) x0 = sp[0];
                    if (k + 1 < n) x1 = sp[NV];
                }
                unsigned int h0 = f2bf(x0), h1 = f2bf(x1);
                float r0 = x0 - bits2f(h0 << 16);
                float r1 = x1 - bits2f(h1 << 16);
                unsigned int l0 = f2bf(r0), l1 = f2bf(r1);
                ((unsigned int*)Xh_lds)[c * (XSTR / 2) + kp] = h0 | (h1 << 16);
                ((unsigned int*)Xl_lds)[c * (XSTR / 2) + kp] = l0 | (l1 << 16);
            }
            __syncthreads();

            short8v a0 = *(const short8v*)&A_lds[((3 * w + 0) * 16 + lr) * ASTR + kg * 8];
            short8v a1 = *(const short8v*)&A_lds[((3 * w + 1) * 16 + lr) * ASTR + kg * 8];
            short8v a2 = *(const short8v*)&A_lds[((3 * w + 2) * 16 + lr) * ASTR + kg * 8];
#pragma unroll
            for (int nt = 0; nt < 4; ++nt) {
                short8v bh = *(const short8v*)&Xh_lds[(nt * 16 + lr) * XSTR + kg * 8];
                short8v bl = *(const short8v*)&Xl_lds[(nt * 16 + lr) * XSTR + kg * 8];
                acc[0][nt] = __builtin_amdgcn_mfma_f32_16x16x32_bf16(a0, bh, acc[0][nt], 0, 0, 0);
                acc[1][nt] = __builtin_amdgcn_mfma_f32_16x16x32_bf16(a1, bh, acc[1][nt], 0, 0, 0);
                acc[2][nt] = __builtin_amdgcn_mfma_f32_16x16x32_bf16(a2, bh, acc[2][nt], 0, 0, 0);
                acc[0][nt] = __builtin_amdgcn_mfma_f32_16x16x32_bf16(a0, bl, acc[0][nt], 0, 0, 0);
                acc[1][nt] = __builtin_amdgcn_mfma_f32_16x16x32_bf16(a1, bl, acc[1][nt], 0, 0, 0);
                acc[2][nt] = __builtin_amdgcn_mfma_f32_16x16x32_bf16(a2, bl, acc[2][nt], 0, 0, 0);
            }
        }

        // epilogue: C/D col=lane&15 (B), row=(lane>>4)*4+reg (mm); emit bf16 hi+lo
#pragma unroll
        for (int i = 0; i < 3; ++i)
#pragma unroll
            for (int nt = 0; nt < 4; ++nt) {
                int c = nt * 16 + lr;
                if (c < 50) {
                    int Brel = bt * 50 + c;
                    int mm0 = (3 * w + i) * 16 + kg * 4;
                    unsigned short* oh = fh_hi + ((size_t)j * 192 + mm0) * cn + Brel;
                    unsigned short* ol = fh_lo + ((size_t)j * 192 + mm0) * cn + Brel;
#pragma unroll
                    for (int r = 0; r < 4; ++r) {
                        float v = acc[i][nt][r];
                        unsigned int h = f2bf(v);
                        unsigned int lo = f2bf(v - bits2f(h << 16));
                        oh[(size_t)r * cn] = (unsigned short)h;
                        ol[(size_t)r * cn] = (unsigned short)lo;
                    }
                }
            }
    }
}

// ---------------- K2 (MFMA): Legendre contraction as bf16 GEMM per m.
// C[l, B] = sum_j leg[l,m,j] * fh[j, m+96pl, B]; planes share A.
// Block: (m = blockIdx.x, B-tile bt = blockIdx.y). 4 waves; wave w owns
// B-cols w*16..w*16+15, all 96 l, both planes.
__global__ __launch_bounds__(256) void leg_mfma_kernel(
    const unsigned short* __restrict__ legh,  // [96 m][96 l][192 j] bf16
    const unsigned short* __restrict__ legl,
    const unsigned short* __restrict__ fh_hi, // [192 j][192 mm][cn] bf16
    const unsigned short* __restrict__ fh_lo,
    unsigned int* __restrict__ out,           // [4][LMAX][MMAX][NV] packed bf16
    int c0, int cn)
{
    __shared__ unsigned short A_lds[2 * 96 * FSTR];       // [hl][l][k]
    __shared__ unsigned short F_lds[2 * 2 * 64 * FSTR];   // [pl][hl][B][k]

    const int m   = blockIdx.x;
    const int bt  = blockIdx.y;
    const int tid = threadIdx.x;
    const int w   = tid >> 6;
    const int l   = tid & 63;
    const int lr  = l & 15;
    const int kg  = l >> 4;

    f32x4 acc[6][2];
#pragma unroll
    for (int lt = 0; lt < 6; ++lt)
#pragma unroll
        for (int pl = 0; pl < 2; ++pl) acc[lt][pl] = (f32x4){0.f, 0.f, 0.f, 0.f};

    const unsigned int* lh32 = (const unsigned int*)legh;
    const unsigned int* ll32 = (const unsigned int*)legl;

    for (int j0 = 0; j0 < NLAT; j0 += 32) {
        __syncthreads();

        // stage A: leg slice [2 hl][96 l][32 k], src [m][l][j] j-contiguous.
        // 3072 uints total = 2 planes x 1536; s<6 -> hi plane, s>=6 -> lo plane
        // (compile-time constant per unrolled iteration; 6*256 = 1536 exactly).
#pragma unroll
        for (int s = 0; s < 12; ++s) {
            const int hl = (s >= 6) ? 1 : 0;
            int rem = tid + 256 * s - 1536 * hl;   // 0..1535
            int lrow = rem >> 4;                   // 0..95
            int ku = rem & 15;                     // 0..15
            const unsigned int* src = hl ? ll32 : lh32;
            unsigned int v = src[((size_t)m * 96 + lrow) * 96 + (j0 >> 1) + ku];
            ((unsigned int*)A_lds)[(size_t)hl * 96 * (FSTR / 2) + lrow * (FSTR / 2) + ku] = v;
        }

        // stage F: [2 pl][2 hl][64 B][32 k] <- fh[j0+jj][m+96pl][bt*50 + 0..49]
        // (B cols 50..63 left stale; they only pollute discarded C columns)
#pragma unroll
        for (int s = 0; s < 13; ++s) {
            int q = tid + 256 * s;
            if (q < 3200) {
                int u  = q % 25;                 // B-pair
                int r2 = q / 25;
                int jj = r2 & 31;
                int r3 = r2 >> 5;
                int pl = r3 & 1;
                int hl = r3 >> 1;
                const unsigned short* src = hl ? fh_lo : fh_hi;
                const unsigned int* s32 = (const unsigned int*)src;
                unsigned int v = s32[((size_t)(j0 + jj) * 192 + m + 96 * pl) * (cn >> 1)
                                     + bt * 25 + u];
                size_t base = ((size_t)(pl * 2 + hl) * 64 + 2 * u) * FSTR + jj;
                F_lds[base]        = (unsigned short)(v & 0xFFFFu);
                F_lds[base + FSTR] = (unsigned short)(v >> 16);
            }
        }
        __syncthreads();

        // frags + MFMA: per plane Fh/Fl; per l-tile Ah/Al; 3 products (hh, hl, lh)
        short8v fH[2], fL[2];
#pragma unroll
        for (int pl = 0; pl < 2; ++pl) {
            fH[pl] = *(const short8v*)&F_lds[((size_t)(pl * 2 + 0) * 64 + w * 16 + lr) * FSTR + kg * 8];
            fL[pl] = *(const short8v*)&F_lds[((size_t)(pl * 2 + 1) * 64 + w * 16 + lr) * FSTR + kg * 8];
        }
#pragma unroll
        for (int lt = 0; lt < 6; ++lt) {
            short8v ah = *(const short8v*)&A_lds[(size_t)(0 * 96 + lt * 16 + lr) * FSTR + kg * 8];
            short8v al = *(const short8v*)&A_lds[(size_t)(1 * 96 + lt * 16 + lr) * FSTR + kg * 8];
#pragma unroll
            for (int pl = 0; pl < 2; ++pl) {
                acc[lt][pl] = __builtin_amdgcn_mfma_f32_16x16x32_bf16(ah, fH[pl], acc[lt][pl], 0, 0, 0);
                acc[lt][pl] = __builtin_amdgcn_mfma_f32_16x16x32_bf16(ah, fL[pl], acc[lt][pl], 0, 0, 0);
                acc[lt][pl] = __builtin_amdgcn_mfma_f32_16x16x32_bf16(al, fH[pl], acc[lt][pl], 0, 0, 0);
            }
        }
    }

    // epilogue: C col = lane&15 = B, row = kg*4+r (within l-tile)
    int c = w * 16 + lr;
    if (c < 50) {
        int B = c0 + bt * 50 + c;
        int bb = B / NV, vv = B % NV;
#pragma unroll
        for (int lt = 0; lt < 6; ++lt) {
#pragma unroll
            for (int r = 0; r < 4; ++r) {
                int ll = lt * 16 + kg * 4 + r;
                out[(((size_t)bb * LMAX + ll) * MMAX + m) * NV + vv] =
                    f2bf(acc[lt][0][r]) | (f2bf(acc[lt][1][r]) << 16);
            }
        }
    }
}

extern "C" void kernel_launch(void* const* d_in, const int* in_sizes, int n_in,
                              void* d_out, int out_size, void* d_ws, size_t ws_size,
                              hipStream_t stream) {
    if (n_in != 3) return;

    const float* data = (const float*)d_in[0];
    const unsigned int* dftw = (const unsigned int*)d_in[1];
    const float* leg  = (const float*)d_in[2];
    unsigned int* out = (unsigned int*)d_out;

    // ws layout: [legh 3.54MB][legl 3.54MB][fh_hi cn*73728B][fh_lo cn*73728B]
    const size_t LEGN = (size_t)96 * 96 * 192;          // shorts per leg plane
    const size_t LEGB = 2 * LEGN * sizeof(unsigned short);
    const size_t rowb = (size_t)192 * 192 * 2 * sizeof(unsigned short); // per B row hi+lo
    if (ws_size < LEGB + 50 * rowb) return;

    unsigned short* legh = (unsigned short*)d_ws;
    unsigned short* legl = legh + LEGN;

    size_t maxrows = (ws_size - LEGB) / rowb;
    int chunk = (int)((maxrows / 50) * 50);
    if (chunk > NB) chunk = NB;

    leg_conv_kernel<<<dim3((96 * 96 * 192 + 255) / 256), dim3(256), 0, stream>>>(
        leg, legh, legl);

    for (int c0 = 0; c0 < NB; c0 += chunk) {
        int cn = NB - c0 < chunk ? NB - c0 : chunk;
        unsigned short* fh_hi = legl + LEGN;
        unsigned short* fh_lo = fh_hi + (size_t)192 * 192 * cn;

        dim3 g1(cn / 50, 96);
        dft_mfma_kernel<<<g1, dim3(256), 0, stream>>>(data, dftw, fh_hi, fh_lo, c0, cn);
        dim3 g2(96, cn / 50);
        leg_mfma_kernel<<<g2, dim3(256), 0, stream>>>(legh, legl, fh_hi, fh_lo, out, c0, cn);
    }
}